// Round 4
// baseline (164.837 us; speedup 1.0000x reference)
//
#include <hip/hip_runtime.h>
#include <hip/hip_bf16.h>

#define BB 4
#define NI 16
#define CC 3
#define HH 256
#define WW 256
#define HWSZ (HH * WW)

// ---------------------------------------------------------------------------
// Kernel 1: per-instance scalars (fp32 inputs).
// inst[i*8 + 0..5] = theta, inst[i*8+6] = coef, [7] = pad.
// coef = instance_valid * (mode in {0,2,4} ? 1 : mode==3 ? alpha : 0)
// (static_like and blink are mutually exclusive in the reference.)
// ---------------------------------------------------------------------------
__global__ void prep_kernel(const float* __restrict__ mode_logits,
                            const float* __restrict__ tp,
                            const float* __restrict__ alpha,
                            const float* __restrict__ iv,
                            float* __restrict__ inst) {
    int i = threadIdx.x;
    if (i >= BB * NI) return;
    float best = mode_logits[i * 5];
    int bid = 0;
#pragma unroll
    for (int k = 1; k < 5; ++k) {
        float v = mode_logits[i * 5 + k];
        if (v > best) { best = v; bid = k; }   // strict > : first max, like jnp.argmax
    }
    float coef;
    if (bid == 0 || bid == 2 || bid == 4)      coef = 1.0f;
    else if (bid == 3)                          coef = alpha[i];
    else                                        coef = 0.0f;
    coef *= iv[i];
#pragma unroll
    for (int k = 0; k < 6; ++k) inst[i * 8 + k] = tp[i * 6 + k];
    inst[i * 8 + 6] = coef;
    inst[i * 8 + 7] = 0.0f;
}

// ---------------------------------------------------------------------------
// Kernel 2: warp + gate + per-instance write + instance-sum fusion.
// One thread per (b, h, w) pixel; loops over NI instances.
// fp32 outputs (harness stores outputs as float32; ref is bf16-quantized
// only for the comparison).
// ---------------------------------------------------------------------------
__global__ __launch_bounds__(256) void warp_main(
    const float* __restrict__ g0,
    const float* __restrict__ m0,
    const float* __restrict__ i_bg,
    const float* __restrict__ inst,
    float* __restrict__ out_gpi,
    float* __restrict__ out_mpi,
    float* __restrict__ out_gmid,
    float* __restrict__ out_mmid,
    float* __restrict__ out_ibase) {
    const int w = threadIdx.x;          // 0..255
    const int h = blockIdx.x;           // 0..255
    const int b = blockIdx.y;           // 0..3
    const int pix = h * WW + w;

    // normalized output-grid coords (align_corners=False)
    const float xs = (2 * w + 1) * (1.0f / WW) - 1.0f;
    const float ys = (2 * h + 1) * (1.0f / HH) - 1.0f;

    float acc[CC] = {0.f, 0.f, 0.f};
    float accm = 0.f;

    for (int ii = 0; ii < NI; ++ii) {
        const int id = b * NI + ii;
        const float* p = inst + id * 8;
        const float coef = p[6];

        float* gp = out_gpi + (size_t)id * CC * HWSZ + pix;
        float* mp = out_mpi + (size_t)id * HWSZ + pix;

        if (coef == 0.0f) {   // wave-uniform branch: gated-off instance writes zeros
            gp[0] = 0.0f; gp[HWSZ] = 0.0f; gp[2 * HWSZ] = 0.0f; mp[0] = 0.0f;
            continue;
        }

        const float gx = p[0] * xs + p[1] * ys + p[2];
        const float gy = p[3] * xs + p[4] * ys + p[5];
        // ix = ((gx+1)*W - 1)/2
        const float ix = gx * (0.5f * WW) + (0.5f * WW - 0.5f);
        const float iy = gy * (0.5f * HH) + (0.5f * HH - 0.5f);
        const float x0f = floorf(ix), y0f = floorf(iy);
        const float wx1 = ix - x0f, wy1 = iy - y0f;
        const float wx0 = 1.0f - wx1, wy0 = 1.0f - wy1;
        const int x0 = (int)x0f, y0 = (int)y0f;
        const bool vx0 = (unsigned)x0 < (unsigned)WW;
        const bool vx1 = (unsigned)(x0 + 1) < (unsigned)WW;
        const bool vy0 = (unsigned)y0 < (unsigned)HH;
        const bool vy1 = (unsigned)(y0 + 1) < (unsigned)HH;
        const bool v00 = vx0 && vy0, v10 = vx1 && vy0;
        const bool v01 = vx0 && vy1, v11 = vx1 && vy1;
        const int o00 = y0 * WW + x0;
        const float w00 = wx0 * wy0, w10 = wx1 * wy0;
        const float w01 = wx0 * wy1, w11 = wx1 * wy1;

        const float* gsrc = g0 + (size_t)id * CC * HWSZ;
        const float* msrc = m0 + (size_t)id * HWSZ;

#pragma unroll
        for (int c = 0; c < CC; ++c) {
            const float* s = gsrc + c * HWSZ;
            const float a00 = v00 ? s[o00] : 0.0f;
            const float a10 = v10 ? s[o00 + 1] : 0.0f;
            const float a01 = v01 ? s[o00 + WW] : 0.0f;
            const float a11 = v11 ? s[o00 + WW + 1] : 0.0f;
            const float val = coef * (w00 * a00 + w10 * a10 + w01 * a01 + w11 * a11);
            gp[c * HWSZ] = val;
            acc[c] += val;
        }
        {
            const float a00 = v00 ? msrc[o00] : 0.0f;
            const float a10 = v10 ? msrc[o00 + 1] : 0.0f;
            const float a01 = v01 ? msrc[o00 + WW] : 0.0f;
            const float a11 = v11 ? msrc[o00 + WW + 1] : 0.0f;
            const float val = coef * (w00 * a00 + w10 * a10 + w01 * a01 + w11 * a11);
            mp[0] = val;
            accm += val;
        }
    }

    const int ob = b * CC * HWSZ + pix;
#pragma unroll
    for (int c = 0; c < CC; ++c) {
        out_gmid[ob + c * HWSZ] = acc[c];
        out_ibase[ob + c * HWSZ] = acc[c] + i_bg[ob + c * HWSZ];
    }
    out_mmid[b * HWSZ + pix] = fminf(fmaxf(accm, 0.0f), 1.0f);
}

extern "C" void kernel_launch(void* const* d_in, const int* in_sizes, int n_in,
                              void* d_out, int out_size, void* d_ws, size_t ws_size,
                              hipStream_t stream) {
    const float* g0          = (const float*)d_in[0];
    const float* m0          = (const float*)d_in[1];
    const float* mode_logits = (const float*)d_in[2];
    const float* tp          = (const float*)d_in[3];
    const float* alpha       = (const float*)d_in[4];
    const float* iv          = (const float*)d_in[5];
    const float* i_bg        = (const float*)d_in[6];

    float* out       = (float*)d_out;
    float* out_gpi   = out;                                        // [B,NI,C,H,W]
    float* out_mpi   = out_gpi  + (size_t)BB * NI * CC * HWSZ;     // [B,NI,1,H,W]
    float* out_gmid  = out_mpi  + (size_t)BB * NI * HWSZ;          // [B,C,H,W]
    float* out_mmid  = out_gmid + (size_t)BB * CC * HWSZ;          // [B,1,H,W]
    float* out_ibase = out_mmid + (size_t)BB * HWSZ;               // [B,C,H,W]

    float* inst = (float*)d_ws;  // 64 * 8 floats

    prep_kernel<<<1, 64, 0, stream>>>(mode_logits, tp, alpha, iv, inst);

    dim3 grid(HH, BB);
    warp_main<<<grid, WW, 0, stream>>>(g0, m0, i_bg, inst,
                                       out_gpi, out_mpi, out_gmid, out_mmid, out_ibase);
}

// Round 5
// 157.576 us; speedup vs baseline: 1.0461x; 1.0461x over previous
//
#include <hip/hip_runtime.h>

#define BB 4
#define NI 16
#define CC 3
#define HH 256
#define WW 256
#define HWSZ (HH * WW)
#define HALF (NI / 2)

// ---------------------------------------------------------------------------
// ws layout:
//   float wsf[0..511]   : per-instance records  id*8 + {theta[6], coef, pad}
//   int   wsi[0..71]    : at wsf+512: [0..7] active count per (b*2+half),
//                         [8 + (b*2+half)*8 + k] active instance idx
//   float part[...]     : at wsf+1024 (byte 4096, 16B aligned):
//                         float4 per ((half*BB + b)*HWSZ + pix) = {c0,c1,c2,m}
// ---------------------------------------------------------------------------

__global__ void prep_kernel(const float* __restrict__ ml,
                            const float* __restrict__ tp,
                            const float* __restrict__ al,
                            const float* __restrict__ iv,
                            float* __restrict__ wsf) {
    __shared__ float scoef[BB * NI];
    const int i = threadIdx.x;                 // 0..63 = b*NI+ii
    float best = ml[i * 5];
    int bid = 0;
#pragma unroll
    for (int k = 1; k < 5; ++k) {
        float v = ml[i * 5 + k];
        if (v > best) { best = v; bid = k; }   // strict >: first max, like jnp.argmax
    }
    float coef = (bid == 0 || bid == 2 || bid == 4) ? 1.0f
               : (bid == 3 ? al[i] : 0.0f);
    coef *= iv[i];
#pragma unroll
    for (int k = 0; k < 6; ++k) wsf[i * 8 + k] = tp[i * 6 + k];
    wsf[i * 8 + 6] = coef;
    wsf[i * 8 + 7] = 0.0f;
    scoef[i] = coef;
    __syncthreads();
    if (i < BB * 2) {                          // one thread per (b, half)
        const int b = i >> 1, half = i & 1;
        int* wsi = (int*)(wsf + 512);
        int cnt = 0;
#pragma unroll
        for (int k = 0; k < HALF; ++k) {
            const int ii = half * HALF + k;
            if (scoef[b * NI + ii] != 0.0f) wsi[8 + i * 8 + cnt++] = ii;
        }
        wsi[i] = cnt;
    }
}

// ---------------------------------------------------------------------------
// Main kernel: one block per (h, b, half); each half warps its 8 instances
// (active-compacted, unrolled x2 for MLP), writes per-instance outputs and a
// float4 partial sum {c0,c1,c2,mask} to ws.
// ---------------------------------------------------------------------------
__global__ __launch_bounds__(256) void warp_half(
    const float* __restrict__ g0,
    const float* __restrict__ m0,
    const float* __restrict__ wsf,
    float* __restrict__ out_gpi,
    float* __restrict__ out_mpi,
    float* __restrict__ part) {
    const int w = threadIdx.x;
    const int h = blockIdx.x;
    const int b = blockIdx.y;
    const int half = blockIdx.z;
    const int pix = h * WW + w;

    const float xs = (2 * w + 1) * (1.0f / WW) - 1.0f;
    const float ys = (2 * h + 1) * (1.0f / HH) - 1.0f;

    const int* wsi = (const int*)(wsf + 512);
    const int lk = b * 2 + half;
    const int nact = wsi[lk];
    const int* act = wsi + 8 + lk * 8;

    float acc0 = 0.f, acc1 = 0.f, acc2 = 0.f, accm = 0.f;

    auto proc = [&](int ii) {
        const int id = b * NI + ii;
        const float* p = wsf + id * 8;
        const float coef = p[6];

        const float gx = p[0] * xs + p[1] * ys + p[2];
        const float gy = p[3] * xs + p[4] * ys + p[5];
        const float ix = gx * (0.5f * WW) + (0.5f * WW - 0.5f);
        const float iy = gy * (0.5f * HH) + (0.5f * HH - 0.5f);
        const float x0f = floorf(ix), y0f = floorf(iy);
        const float wx1 = ix - x0f, wy1 = iy - y0f;
        const float wx0 = 1.0f - wx1, wy0 = 1.0f - wy1;
        const int x0 = (int)x0f, y0 = (int)y0f;
        const bool vx0 = (unsigned)x0 < (unsigned)WW;
        const bool vx1 = (unsigned)(x0 + 1) < (unsigned)WW;
        const bool vy0 = (unsigned)y0 < (unsigned)HH;
        const bool vy1 = (unsigned)(y0 + 1) < (unsigned)HH;
        const bool v00 = vx0 && vy0, v10 = vx1 && vy0;
        const bool v01 = vx0 && vy1, v11 = vx1 && vy1;
        const int o00 = y0 * WW + x0;
        const float w00 = wx0 * wy0, w10 = wx1 * wy0;
        const float w01 = wx0 * wy1, w11 = wx1 * wy1;

        const float* gsrc = g0 + (size_t)id * CC * HWSZ;
        const float* msrc = m0 + (size_t)id * HWSZ;
        float* gp = out_gpi + (size_t)id * CC * HWSZ + pix;

        // issue all 16 taps (independent) before consuming
        const float a00_0 = v00 ? gsrc[o00] : 0.0f;
        const float a10_0 = v10 ? gsrc[o00 + 1] : 0.0f;
        const float a01_0 = v01 ? gsrc[o00 + WW] : 0.0f;
        const float a11_0 = v11 ? gsrc[o00 + WW + 1] : 0.0f;
        const float a00_1 = v00 ? gsrc[HWSZ + o00] : 0.0f;
        const float a10_1 = v10 ? gsrc[HWSZ + o00 + 1] : 0.0f;
        const float a01_1 = v01 ? gsrc[HWSZ + o00 + WW] : 0.0f;
        const float a11_1 = v11 ? gsrc[HWSZ + o00 + WW + 1] : 0.0f;
        const float a00_2 = v00 ? gsrc[2 * HWSZ + o00] : 0.0f;
        const float a10_2 = v10 ? gsrc[2 * HWSZ + o00 + 1] : 0.0f;
        const float a01_2 = v01 ? gsrc[2 * HWSZ + o00 + WW] : 0.0f;
        const float a11_2 = v11 ? gsrc[2 * HWSZ + o00 + WW + 1] : 0.0f;
        const float m00 = v00 ? msrc[o00] : 0.0f;
        const float m10 = v10 ? msrc[o00 + 1] : 0.0f;
        const float m01 = v01 ? msrc[o00 + WW] : 0.0f;
        const float m11 = v11 ? msrc[o00 + WW + 1] : 0.0f;

        const float val0 = coef * (w00 * a00_0 + w10 * a10_0 + w01 * a01_0 + w11 * a11_0);
        const float val1 = coef * (w00 * a00_1 + w10 * a10_1 + w01 * a01_1 + w11 * a11_1);
        const float val2 = coef * (w00 * a00_2 + w10 * a10_2 + w01 * a01_2 + w11 * a11_2);
        const float valm = coef * (w00 * m00 + w10 * m10 + w01 * m01 + w11 * m11);

        gp[0] = val0; gp[HWSZ] = val1; gp[2 * HWSZ] = val2;
        out_mpi[(size_t)id * HWSZ + pix] = valm;
        acc0 += val0; acc1 += val1; acc2 += val2; accm += valm;
    };

    int k = 0;
    for (; k + 2 <= nact; k += 2) { proc(act[k]); proc(act[k + 1]); }
    if (k < nact) proc(act[k]);

    // gated instances in my half: zero per-instance outputs
#pragma unroll
    for (int kk = 0; kk < HALF; ++kk) {
        const int ii = half * HALF + kk;
        const int id = b * NI + ii;
        if (wsf[id * 8 + 6] == 0.0f) {
            float* gp = out_gpi + (size_t)id * CC * HWSZ + pix;
            gp[0] = 0.0f; gp[HWSZ] = 0.0f; gp[2 * HWSZ] = 0.0f;
            out_mpi[(size_t)id * HWSZ + pix] = 0.0f;
        }
    }

    float4 pv; pv.x = acc0; pv.y = acc1; pv.z = acc2; pv.w = accm;
    ((float4*)part)[(size_t)(half * BB + b) * HWSZ + pix] = pv;
}

// ---------------------------------------------------------------------------
// Combine: g_mid / m_mid / i_base from the two half-partials.
// ---------------------------------------------------------------------------
__global__ __launch_bounds__(256) void combine_k(
    const float* __restrict__ part,
    const float* __restrict__ i_bg,
    float* __restrict__ out_gmid,
    float* __restrict__ out_mmid,
    float* __restrict__ out_ibase) {
    const int w = threadIdx.x;
    const int h = blockIdx.x;
    const int b = blockIdx.y;
    const int pix = h * WW + w;
    const float4 p0 = ((const float4*)part)[(size_t)b * HWSZ + pix];
    const float4 p1 = ((const float4*)part)[(size_t)(BB + b) * HWSZ + pix];
    const float s0 = p0.x + p1.x, s1 = p0.y + p1.y, s2 = p0.z + p1.z;
    const float sm = p0.w + p1.w;
    const int ob = b * CC * HWSZ + pix;
    out_gmid[ob] = s0;
    out_gmid[ob + HWSZ] = s1;
    out_gmid[ob + 2 * HWSZ] = s2;
    out_ibase[ob] = s0 + i_bg[ob];
    out_ibase[ob + HWSZ] = s1 + i_bg[ob + HWSZ];
    out_ibase[ob + 2 * HWSZ] = s2 + i_bg[ob + 2 * HWSZ];
    out_mmid[b * HWSZ + pix] = fminf(fmaxf(sm, 0.0f), 1.0f);
}

// ---------------------------------------------------------------------------
// Fallback (round-4 fused kernel) if ws is too small for partials.
// ---------------------------------------------------------------------------
__global__ __launch_bounds__(256) void warp_fused(
    const float* __restrict__ g0, const float* __restrict__ m0,
    const float* __restrict__ i_bg, const float* __restrict__ inst,
    float* __restrict__ out_gpi, float* __restrict__ out_mpi,
    float* __restrict__ out_gmid, float* __restrict__ out_mmid,
    float* __restrict__ out_ibase) {
    const int w = threadIdx.x, h = blockIdx.x, b = blockIdx.y;
    const int pix = h * WW + w;
    const float xs = (2 * w + 1) * (1.0f / WW) - 1.0f;
    const float ys = (2 * h + 1) * (1.0f / HH) - 1.0f;
    float acc[CC] = {0.f, 0.f, 0.f}; float accm = 0.f;
    for (int ii = 0; ii < NI; ++ii) {
        const int id = b * NI + ii;
        const float* p = inst + id * 8;
        const float coef = p[6];
        float* gp = out_gpi + (size_t)id * CC * HWSZ + pix;
        float* mp = out_mpi + (size_t)id * HWSZ + pix;
        if (coef == 0.0f) { gp[0] = 0.f; gp[HWSZ] = 0.f; gp[2 * HWSZ] = 0.f; mp[0] = 0.f; continue; }
        const float gx = p[0] * xs + p[1] * ys + p[2];
        const float gy = p[3] * xs + p[4] * ys + p[5];
        const float ix = gx * (0.5f * WW) + (0.5f * WW - 0.5f);
        const float iy = gy * (0.5f * HH) + (0.5f * HH - 0.5f);
        const float x0f = floorf(ix), y0f = floorf(iy);
        const float wx1 = ix - x0f, wy1 = iy - y0f;
        const float wx0 = 1.0f - wx1, wy0 = 1.0f - wy1;
        const int x0 = (int)x0f, y0 = (int)y0f;
        const bool vx0 = (unsigned)x0 < (unsigned)WW, vx1 = (unsigned)(x0 + 1) < (unsigned)WW;
        const bool vy0 = (unsigned)y0 < (unsigned)HH, vy1 = (unsigned)(y0 + 1) < (unsigned)HH;
        const bool v00 = vx0 && vy0, v10 = vx1 && vy0, v01 = vx0 && vy1, v11 = vx1 && vy1;
        const int o00 = y0 * WW + x0;
        const float w00 = wx0 * wy0, w10 = wx1 * wy0, w01 = wx0 * wy1, w11 = wx1 * wy1;
        const float* gsrc = g0 + (size_t)id * CC * HWSZ;
        const float* msrc = m0 + (size_t)id * HWSZ;
#pragma unroll
        for (int c = 0; c < CC; ++c) {
            const float* s = gsrc + c * HWSZ;
            const float val = coef * (w00 * (v00 ? s[o00] : 0.f) + w10 * (v10 ? s[o00 + 1] : 0.f)
                                    + w01 * (v01 ? s[o00 + WW] : 0.f) + w11 * (v11 ? s[o00 + WW + 1] : 0.f));
            gp[c * HWSZ] = val; acc[c] += val;
        }
        const float valm = coef * (w00 * (v00 ? msrc[o00] : 0.f) + w10 * (v10 ? msrc[o00 + 1] : 0.f)
                                 + w01 * (v01 ? msrc[o00 + WW] : 0.f) + w11 * (v11 ? msrc[o00 + WW + 1] : 0.f));
        mp[0] = valm; accm += valm;
    }
    const int ob = b * CC * HWSZ + pix;
#pragma unroll
    for (int c = 0; c < CC; ++c) {
        out_gmid[ob + c * HWSZ] = acc[c];
        out_ibase[ob + c * HWSZ] = acc[c] + i_bg[ob + c * HWSZ];
    }
    out_mmid[b * HWSZ + pix] = fminf(fmaxf(accm, 0.0f), 1.0f);
}

extern "C" void kernel_launch(void* const* d_in, const int* in_sizes, int n_in,
                              void* d_out, int out_size, void* d_ws, size_t ws_size,
                              hipStream_t stream) {
    const float* g0          = (const float*)d_in[0];
    const float* m0          = (const float*)d_in[1];
    const float* mode_logits = (const float*)d_in[2];
    const float* tp          = (const float*)d_in[3];
    const float* alpha       = (const float*)d_in[4];
    const float* iv          = (const float*)d_in[5];
    const float* i_bg        = (const float*)d_in[6];

    float* out       = (float*)d_out;
    float* out_gpi   = out;                                        // [B,NI,C,H,W]
    float* out_mpi   = out_gpi  + (size_t)BB * NI * CC * HWSZ;     // [B,NI,1,H,W]
    float* out_gmid  = out_mpi  + (size_t)BB * NI * HWSZ;          // [B,C,H,W]
    float* out_mmid  = out_gmid + (size_t)BB * CC * HWSZ;          // [B,1,H,W]
    float* out_ibase = out_mmid + (size_t)BB * HWSZ;               // [B,C,H,W]

    float* wsf  = (float*)d_ws;
    float* part = wsf + 1024;                                      // 16B-aligned
    const size_t need = 4096 + (size_t)2 * BB * HWSZ * 4 * sizeof(float);

    prep_kernel<<<1, 64, 0, stream>>>(mode_logits, tp, alpha, iv, wsf);

    if (ws_size >= need) {
        dim3 grid(HH, BB, 2);
        warp_half<<<grid, WW, 0, stream>>>(g0, m0, wsf, out_gpi, out_mpi, part);
        dim3 grid2(HH, BB);
        combine_k<<<grid2, WW, 0, stream>>>(part, i_bg, out_gmid, out_mmid, out_ibase);
    } else {
        dim3 grid(HH, BB);
        warp_fused<<<grid, WW, 0, stream>>>(g0, m0, i_bg, wsf, out_gpi, out_mpi,
                                            out_gmid, out_mmid, out_ibase);
    }
}

// Round 6
// 156.359 us; speedup vs baseline: 1.0542x; 1.0078x over previous
//
#include <hip/hip_runtime.h>

#define BB 4
#define NI 16
#define CC 3
#define HH 256
#define WW 256
#define HWSZ (HH * WW)

// ---------------------------------------------------------------------------
// ws layout: float wsf[id*8 + {theta[6], coef, pad}]  (64 * 8 floats)
// ---------------------------------------------------------------------------
__global__ void prep_kernel(const float* __restrict__ ml,
                            const float* __restrict__ tp,
                            const float* __restrict__ al,
                            const float* __restrict__ iv,
                            float* __restrict__ wsf) {
    const int i = threadIdx.x;                 // 0..63 = b*NI+ii
    if (i >= BB * NI) return;
    float best = ml[i * 5];
    int bid = 0;
#pragma unroll
    for (int k = 1; k < 5; ++k) {
        float v = ml[i * 5 + k];
        if (v > best) { best = v; bid = k; }   // strict >: first max, like jnp.argmax
    }
    float coef = (bid == 0 || bid == 2 || bid == 4) ? 1.0f
               : (bid == 3 ? al[i] : 0.0f);
    coef *= iv[i];
#pragma unroll
    for (int k = 0; k < 6; ++k) wsf[i * 8 + k] = tp[i * 6 + k];
    wsf[i * 8 + 6] = coef;
    wsf[i * 8 + 7] = 0.0f;
}

// ---------------------------------------------------------------------------
// K1: one block per (row, global-instance). Perfectly uniform work per block;
// inactive instances are pure zero-fill streaming. Writes gpi/mpi only.
// ---------------------------------------------------------------------------
__global__ __launch_bounds__(256) void warp_inst(
    const float* __restrict__ g0,
    const float* __restrict__ m0,
    const float* __restrict__ wsf,
    float* __restrict__ out_gpi,
    float* __restrict__ out_mpi) {
    const int w = threadIdx.x;                 // 0..255
    const int h = blockIdx.x;                  // 0..255
    const int id = blockIdx.y;                 // 0..63 (= b*NI+ii)
    const int pix = h * WW + w;

    const float* p = wsf + id * 8;
    const float coef = p[6];

    float* gp = out_gpi + (size_t)id * CC * HWSZ + pix;
    float* mp = out_mpi + (size_t)id * HWSZ + pix;

    if (coef == 0.0f) {                        // block-uniform: streaming zero-fill
        gp[0] = 0.0f; gp[HWSZ] = 0.0f; gp[2 * HWSZ] = 0.0f; mp[0] = 0.0f;
        return;
    }

    const float xs = (2 * w + 1) * (1.0f / WW) - 1.0f;
    const float ys = (2 * h + 1) * (1.0f / HH) - 1.0f;

    const float gx = p[0] * xs + p[1] * ys + p[2];
    const float gy = p[3] * xs + p[4] * ys + p[5];
    const float ix = gx * (0.5f * WW) + (0.5f * WW - 0.5f);
    const float iy = gy * (0.5f * HH) + (0.5f * HH - 0.5f);
    const float x0f = floorf(ix), y0f = floorf(iy);
    const float wx1 = ix - x0f, wy1 = iy - y0f;
    const float wx0 = 1.0f - wx1, wy0 = 1.0f - wy1;
    const int x0 = (int)x0f, y0 = (int)y0f;
    const bool vx0 = (unsigned)x0 < (unsigned)WW;
    const bool vx1 = (unsigned)(x0 + 1) < (unsigned)WW;
    const bool vy0 = (unsigned)y0 < (unsigned)HH;
    const bool vy1 = (unsigned)(y0 + 1) < (unsigned)HH;
    const bool v00 = vx0 && vy0, v10 = vx1 && vy0;
    const bool v01 = vx0 && vy1, v11 = vx1 && vy1;
    const int o00 = y0 * WW + x0;
    const float w00 = wx0 * wy0, w10 = wx1 * wy0;
    const float w01 = wx0 * wy1, w11 = wx1 * wy1;

    const float* gsrc = g0 + (size_t)id * CC * HWSZ;
    const float* msrc = m0 + (size_t)id * HWSZ;

    // 16 independent gathers, issued before any consumption
    const float a00_0 = v00 ? gsrc[o00] : 0.0f;
    const float a10_0 = v10 ? gsrc[o00 + 1] : 0.0f;
    const float a01_0 = v01 ? gsrc[o00 + WW] : 0.0f;
    const float a11_0 = v11 ? gsrc[o00 + WW + 1] : 0.0f;
    const float a00_1 = v00 ? gsrc[HWSZ + o00] : 0.0f;
    const float a10_1 = v10 ? gsrc[HWSZ + o00 + 1] : 0.0f;
    const float a01_1 = v01 ? gsrc[HWSZ + o00 + WW] : 0.0f;
    const float a11_1 = v11 ? gsrc[HWSZ + o00 + WW + 1] : 0.0f;
    const float a00_2 = v00 ? gsrc[2 * HWSZ + o00] : 0.0f;
    const float a10_2 = v10 ? gsrc[2 * HWSZ + o00 + 1] : 0.0f;
    const float a01_2 = v01 ? gsrc[2 * HWSZ + o00 + WW] : 0.0f;
    const float a11_2 = v11 ? gsrc[2 * HWSZ + o00 + WW + 1] : 0.0f;
    const float m00 = v00 ? msrc[o00] : 0.0f;
    const float m10 = v10 ? msrc[o00 + 1] : 0.0f;
    const float m01 = v01 ? msrc[o00 + WW] : 0.0f;
    const float m11 = v11 ? msrc[o00 + WW + 1] : 0.0f;

    gp[0]        = coef * (w00 * a00_0 + w10 * a10_0 + w01 * a01_0 + w11 * a11_0);
    gp[HWSZ]     = coef * (w00 * a00_1 + w10 * a10_1 + w01 * a01_1 + w11 * a11_1);
    gp[2 * HWSZ] = coef * (w00 * a00_2 + w10 * a10_2 + w01 * a01_2 + w11 * a11_2);
    mp[0]        = coef * (w00 * m00 + w10 * m10 + w01 * m01 + w11 * m11);
}

// ---------------------------------------------------------------------------
// K2: reduce over the 16 instances (gpi/mpi are L3-warm from K1), produce
// g_mid / m_mid / i_base.
// ---------------------------------------------------------------------------
__global__ __launch_bounds__(256) void combine_k(
    const float* __restrict__ gpi,
    const float* __restrict__ mpi,
    const float* __restrict__ i_bg,
    float* __restrict__ out_gmid,
    float* __restrict__ out_mmid,
    float* __restrict__ out_ibase) {
    const int w = threadIdx.x;
    const int h = blockIdx.x;
    const int b = blockIdx.y;
    const int pix = h * WW + w;

    float s0 = 0.f, s1 = 0.f, s2 = 0.f, sm = 0.f;
#pragma unroll
    for (int ii = 0; ii < NI; ++ii) {
        const size_t gb = (size_t)(b * NI + ii) * CC * HWSZ + pix;
        s0 += gpi[gb];
        s1 += gpi[gb + HWSZ];
        s2 += gpi[gb + 2 * HWSZ];
        sm += mpi[(size_t)(b * NI + ii) * HWSZ + pix];
    }
    const int ob = b * CC * HWSZ + pix;
    out_gmid[ob] = s0;
    out_gmid[ob + HWSZ] = s1;
    out_gmid[ob + 2 * HWSZ] = s2;
    out_ibase[ob] = s0 + i_bg[ob];
    out_ibase[ob + HWSZ] = s1 + i_bg[ob + HWSZ];
    out_ibase[ob + 2 * HWSZ] = s2 + i_bg[ob + 2 * HWSZ];
    out_mmid[b * HWSZ + pix] = fminf(fmaxf(sm, 0.0f), 1.0f);
}

extern "C" void kernel_launch(void* const* d_in, const int* in_sizes, int n_in,
                              void* d_out, int out_size, void* d_ws, size_t ws_size,
                              hipStream_t stream) {
    const float* g0          = (const float*)d_in[0];
    const float* m0          = (const float*)d_in[1];
    const float* mode_logits = (const float*)d_in[2];
    const float* tp          = (const float*)d_in[3];
    const float* alpha       = (const float*)d_in[4];
    const float* iv          = (const float*)d_in[5];
    const float* i_bg        = (const float*)d_in[6];

    float* out       = (float*)d_out;
    float* out_gpi   = out;                                        // [B,NI,C,H,W]
    float* out_mpi   = out_gpi  + (size_t)BB * NI * CC * HWSZ;     // [B,NI,1,H,W]
    float* out_gmid  = out_mpi  + (size_t)BB * NI * HWSZ;          // [B,C,H,W]
    float* out_mmid  = out_gmid + (size_t)BB * CC * HWSZ;          // [B,1,H,W]
    float* out_ibase = out_mmid + (size_t)BB * HWSZ;               // [B,C,H,W]

    float* wsf = (float*)d_ws;  // 64*8 floats

    prep_kernel<<<1, 64, 0, stream>>>(mode_logits, tp, alpha, iv, wsf);

    dim3 grid1(HH, BB * NI);
    warp_inst<<<grid1, WW, 0, stream>>>(g0, m0, wsf, out_gpi, out_mpi);

    dim3 grid2(HH, BB);
    combine_k<<<grid2, WW, 0, stream>>>(out_gpi, out_mpi, i_bg,
                                        out_gmid, out_mmid, out_ibase);
}